// Round 3
// baseline (370.058 us; speedup 1.0000x reference)
//
#include <hip/hip_runtime.h>
#include <hip/hip_bf16.h>
#include <stdint.h>

// Problem constants
#define Bn   32
#define CIN  128
#define Hh   56
#define Ww   56
#define COUT 256
#define HP   58      // padded H (1 each side)
#define WP   58      // padded W
#define KTOT 1152    // 3*3*128, k = kh*384 + kw*128 + ci
#define NTOT (Bn * Hh * Ww)   // 100352

typedef __attribute__((ext_vector_type(8))) short short8;     // 8 x bf16
typedef __attribute__((ext_vector_type(4))) float floatx4;

// ---------------------------------------------------------------------------
// Pre-pass 1: x NCHW fp32 -> zero-padded NHWC bf16  xpad[b][hp][wp][ci]
// ---------------------------------------------------------------------------
__global__ __launch_bounds__(256) void xform_x(const float* __restrict__ x,
                                               __hip_bfloat16* __restrict__ xp) {
  __shared__ __hip_bfloat16 t[WP * 130];   // [w_out][ci], stride 130 (4B-aligned rows)
  const int bid = blockIdx.x;
  const int b = bid / HP, hp = bid % HP;
  const size_t obase = (size_t)bid * (WP * CIN);
  const int tid = threadIdx.x;

  if (hp == 0 || hp == HP - 1) {            // top/bottom padding rows
    uint4 z = {0u, 0u, 0u, 0u};
    uint4* o = (uint4*)(xp + obase);
    for (int i = tid; i < (WP * CIN) / 8; i += 256) o[i] = z;
    return;
  }
  const int h = hp - 1;

  // zero the left/right pad columns (t rows 0 and 57)
  {
    const int r = (tid >> 7) * (WP - 1);    // tid<128 -> row 0, else row 57
    const int ci = tid & 127;
    t[r * 130 + ci] = __float2bfloat16(0.0f);
  }

  // fill t rows 1..56 from x: float4 along w, transpose into [w][ci]
  const float* xrow = x + (size_t)b * (CIN * Hh * Ww) + h * Ww;
  for (int i = tid; i < CIN * 14; i += 256) {   // 14 float4 per ci row
    const int ci = i / 14, wq = i - ci * 14;
    const float4 v = *(const float4*)(xrow + (size_t)ci * (Hh * Ww) + wq * 4);
    const int wr = 1 + wq * 4;
    t[(wr + 0) * 130 + ci] = __float2bfloat16(v.x);
    t[(wr + 1) * 130 + ci] = __float2bfloat16(v.y);
    t[(wr + 2) * 130 + ci] = __float2bfloat16(v.z);
    t[(wr + 3) * 130 + ci] = __float2bfloat16(v.w);
  }
  __syncthreads();

  // write out: 8 bf16 (16B) per chunk, ci-contiguous, coalesced
  for (int i = tid; i < (WP * CIN) / 8; i += 256) {
    const int wo = i >> 4, c8 = (i & 15) * 8;
    const uint32_t* src = (const uint32_t*)&t[wo * 130 + c8];
    uint4 d;
    d.x = src[0]; d.y = src[1]; d.z = src[2]; d.w = src[3];
    *(uint4*)(xp + obase + (size_t)wo * CIN + c8) = d;
  }
}

// ---------------------------------------------------------------------------
// Pre-pass 2: weights OIHW fp32 -> wt[co][kh][kw][ci] bf16 (row-major 256x1152)
// ---------------------------------------------------------------------------
__global__ __launch_bounds__(256) void xform_w(const float* __restrict__ w,
                                               __hip_bfloat16* __restrict__ wt) {
  const int idx = blockIdx.x * 256 + threadIdx.x;   // grid sized exactly 256*1152
  const int co = idx / KTOT, k = idx - co * KTOT;
  const int kh = k / 384, r = k - kh * 384, kw = r >> 7, ci = r & 127;
  wt[idx] = __float2bfloat16(w[((co * CIN + ci) * 3 + kh) * 3 + kw]);
}

// ---------------------------------------------------------------------------
// Implicit GEMM, LDS-FREE: fragments loaded directly from global (L2-resident).
//   C[m=co][n=(b,h,w)] = sum_k A[m][k] * B[k][n] + bias
//   A-frag: lane reads wt[row][k0+fk .. +8)   -> 16 rows x 64B per wave-load
//   B-frag: lane reads xpad[pix][bOff+fk ..+8) -> 16 pixel-rows x 64B per load
// Identical bytes to the LDS round-trip path (same fm/fk mapping) -> results
// are bit-identical to the verified R1/R2 kernels. No barriers in the K-loop:
// the compiler interleaves global_load_dwordx4 with MFMA under fine vmcnt.
// 128x128 block tile, 4 waves of 64x64 (4x4 of 16x16x32 bf16).
// ---------------------------------------------------------------------------
__global__ __launch_bounds__(256, 3) void conv_gemm(const __hip_bfloat16* __restrict__ wt,
                                                    const __hip_bfloat16* __restrict__ xp,
                                                    const float* __restrict__ bias,
                                                    float* __restrict__ y) {
  const int tid  = threadIdx.x;
  const int lane = tid & 63, wv = tid >> 6;

  // XCD-aware swizzle: gid and gid+8 share bn (same B tile, bm=0/1) and land
  // on the same XCD under round-robin %8 dispatch. Bijective over 1568 blocks.
  const int gid = blockIdx.x;
  const int bm = (gid >> 3) & 1;
  const int bn = (gid & 7) | ((gid >> 4) << 3);
  const int m0 = bm * 128, n0 = bn * 128;

  const int fm = lane & 15, fk = (lane >> 4) * 8;
  const int waveM = wv & 1, waveN = wv >> 1;

  // A fragment row pointers (k advances by immediate offsets)
  const __hip_bfloat16* aP[4];
#pragma unroll
  for (int i = 0; i < 4; ++i)
    aP[i] = wt + (size_t)(m0 + waveM * 64 + i * 16 + fm) * KTOT + fk;

  // B fragment pixel pointers
  const __hip_bfloat16* bP[4];
#pragma unroll
  for (int j = 0; j < 4; ++j) {
    const int n = n0 + waveN * 64 + j * 16 + fm;
    const int b = n / 3136, r = n - b * 3136, h = r / 56, w = r - h * 56;
    bP[j] = xp + (size_t)((b * HP + h) * WP + w) * CIN + fk;
  }

  floatx4 acc[4][4];
#pragma unroll
  for (int i = 0; i < 4; ++i)
#pragma unroll
    for (int j = 0; j < 4; ++j) acc[i][j] = (floatx4){0.f, 0.f, 0.f, 0.f};

#pragma unroll
  for (int kt = 0; kt < 36; ++kt) {
    // chunk kt covers k = [kt*32, kt*32+32): fixed (kh,kw), ci0 = (kt&3)*32
    const int kh = kt / 12, kw = (kt >> 2) % 3, ci0 = (kt & 3) * 32;
    const int aO = kt * 32;                      // elements into wt row
    const int bO = (kh * WP + kw) * CIN + ci0;   // elements into xpad

    short8 a[4], b[4];
#pragma unroll
    for (int i = 0; i < 4; ++i) a[i] = *(const short8*)(aP[i] + aO);
#pragma unroll
    for (int j = 0; j < 4; ++j) b[j] = *(const short8*)(bP[j] + bO);
#pragma unroll
    for (int i = 0; i < 4; ++i)
#pragma unroll
      for (int j = 0; j < 4; ++j)
        acc[i][j] = __builtin_amdgcn_mfma_f32_16x16x32_bf16(a[i], b[j], acc[i][j], 0, 0, 0);
  }

  // ---- epilogue: D[row][col], col = lane&15 (n), row = (lane>>4)*4 + reg (m)
  const int col = lane & 15, quad = lane >> 4;
#pragma unroll
  for (int j = 0; j < 4; ++j) {
    const int n = n0 + waveN * 64 + j * 16 + col;
    const int bb = n / 3136, nr = n - bb * 3136;
    const size_t base = (size_t)bb * (COUT * 3136) + nr;
#pragma unroll
    for (int i = 0; i < 4; ++i) {
      const int co0 = m0 + waveM * 64 + i * 16 + quad * 4;
      const floatx4 b4 = *(const floatx4*)&bias[co0];
#pragma unroll
      for (int r = 0; r < 4; ++r) {
        y[base + (size_t)(co0 + r) * 3136] = acc[i][j][r] + b4[r];
      }
    }
  }
}

extern "C" void kernel_launch(void* const* d_in, const int* in_sizes, int n_in,
                              void* d_out, int out_size, void* d_ws, size_t ws_size,
                              hipStream_t stream) {
  const float* x = (const float*)d_in[0];
  const float* w = (const float*)d_in[1];
  const float* b = (const float*)d_in[2];
  float* y = (float*)d_out;

  const size_t xpad_bytes = (size_t)Bn * HP * WP * CIN * sizeof(__hip_bfloat16); // 27.55 MB
  __hip_bfloat16* xp = (__hip_bfloat16*)d_ws;
  __hip_bfloat16* wt = (__hip_bfloat16*)((char*)d_ws + xpad_bytes);              // +0.59 MB

  xform_x<<<Bn * HP, 256, 0, stream>>>(x, xp);
  xform_w<<<(COUT * KTOT) / 256, 256, 0, stream>>>(w, wt);
  conv_gemm<<<2 * (NTOT / 128), 256, 0, stream>>>(wt, xp, b, y);
}

// Round 5
// 284.570 us; speedup vs baseline: 1.3004x; 1.3004x over previous
//
#include <hip/hip_runtime.h>
#include <hip/hip_bf16.h>
#include <stdint.h>

// Problem constants
#define Bn   32
#define CIN  128
#define Hh   56
#define Ww   56
#define COUT 256
#define HP   58            // padded rows (1 top + 1 bottom)
#define WP   58            // padded row width: 0=pad, 1..56 data, 57=pad  (PROVEN 28.1MB ws footprint)
#define ROWB (WP*CIN)      // 7424 elements per padded row
#define NCHUNK 36          // K chunks of 32: (ci-half 2) x (kh 3) x (kw 3) x (ci32 2)
#define PIXSTRIDE 144      // region bytes per pixel slot: 128 payload (64 ci) + 16 pad

typedef __attribute__((ext_vector_type(8))) short short8;     // 8 x bf16
typedef __attribute__((ext_vector_type(4))) float floatx4;

// ---------------------------------------------------------------------------
// Pre-pass 1 (R2-proven): x NCHW fp32 -> zero-padded NHWC bf16 xpad[b][hp][w'][ci]
// ---------------------------------------------------------------------------
__global__ __launch_bounds__(256) void xform_x(const float* __restrict__ x,
                                               __hip_bfloat16* __restrict__ xp) {
  __shared__ __hip_bfloat16 t[WP * 130];   // [w_out][ci]
  const int bid = blockIdx.x;              // 32*58 blocks
  const int b = bid / HP, hp = bid % HP;
  const size_t obase = (size_t)bid * ROWB;
  const int tid = threadIdx.x;

  if (hp == 0 || hp == HP - 1) {           // top/bottom pad rows
    uint4 z = {0u, 0u, 0u, 0u};
    uint4* o = (uint4*)(xp + obase);
    for (int i = tid; i < ROWB / 8; i += 256) o[i] = z;
    return;
  }
  const int h = hp - 1;

  { // zero w_out rows 0 and 57 (left/right pad)
    const int r = (tid >> 7) * (WP - 1);
    const int ci = tid & 127;
    t[r * 130 + ci] = __float2bfloat16(0.0f);
  }
  // fill w_out 1..56 from x, float4 along w, transpose into [w][ci]
  const float* xrow = x + (size_t)b * (CIN * Hh * Ww) + h * Ww;
  for (int i = tid; i < CIN * 14; i += 256) {
    const int ci = i / 14, wq = i - ci * 14;
    const float4 v = *(const float4*)(xrow + (size_t)ci * (Hh * Ww) + wq * 4);
    const int wr = 1 + wq * 4;
    t[(wr + 0) * 130 + ci] = __float2bfloat16(v.x);
    t[(wr + 1) * 130 + ci] = __float2bfloat16(v.y);
    t[(wr + 2) * 130 + ci] = __float2bfloat16(v.z);
    t[(wr + 3) * 130 + ci] = __float2bfloat16(v.w);
  }
  __syncthreads();
  // write out: 8 bf16 (16B) per chunk, ci-contiguous, coalesced
  for (int i = tid; i < ROWB / 8; i += 256) {
    const int wo = i >> 4, c8 = (i & 15) * 8;
    const uint32_t* src = (const uint32_t*)&t[wo * 130 + c8];
    uint4 d;
    d.x = src[0]; d.y = src[1]; d.z = src[2]; d.w = src[3];
    *(uint4*)(xp + obase + (size_t)wo * CIN + c8) = d;
  }
}

// ---------------------------------------------------------------------------
// Pre-pass 2: weights OIHW fp32 -> FRAGMENT-ORDERED wtf.
//   wtf[kt][mb][lane][e]: A-frag for chunk kt, m-block mb (16 rows) is one
//   contiguous 1KB wave-load (base + lane*16B).
//   chunk order: kt = h*18 + kh*6 + kw*2 + (ci32/32); k-in-chunk = q*8+e -> ci
// ---------------------------------------------------------------------------
__global__ __launch_bounds__(256) void xform_w(const float* __restrict__ w,
                                               __hip_bfloat16* __restrict__ wtf) {
  const int o = blockIdx.x * 256 + threadIdx.x;   // grid = 294912/256 = 1152
  const int e = o & 7, lane = (o >> 3) & 63, mb = (o >> 9) & 15, kt = o >> 13;
  const int q = lane >> 4, fm = lane & 15;
  const int h = kt / 18, rem = kt % 18;
  const int kh = rem / 6, rem2 = rem % 6, kw = rem2 >> 1, ci32 = (rem2 & 1) * 32;
  const int m = mb * 16 + fm;
  const int ci = h * 64 + ci32 + q * 8 + e;
  wtf[o] = __float2bfloat16(w[((m * CIN + ci) * 3 + kh) * 3 + kw]);
}

// ---------------------------------------------------------------------------
// Conv GEMM, region-resident B + direct-prefetched A:
//   block = (b, hpair, bm): 128 co x 128 n' (2 output rows x 64 w-slots,
//   slots 56..63 are garbage, masked at epilogue)
//   LDS: 4 xpad rows x 64 pixel slots per ci-half (36.9KB), staged once per
//   half; slots >=58 zero-filled in LDS. K-loop: 36 chunks, 3 barriers total.
//   A-frags: contiguous 1KB wave-loads from fragment-ordered wtf (L2-hot),
//   2-slot register prefetch pipeline.
// ---------------------------------------------------------------------------
__global__ __launch_bounds__(256, 3) void conv_gemm(const __hip_bfloat16* __restrict__ wtf,
                                                    const __hip_bfloat16* __restrict__ xp,
                                                    const float* __restrict__ bias,
                                                    float* __restrict__ y) {
  __shared__ __align__(16) char region[256 * PIXSTRIDE];   // 36864 B

  const int tid  = threadIdx.x;
  const int lane = tid & 63, wv = tid >> 6;
  const int fm = lane & 15, q = lane >> 4;
  const int waveM = wv & 1, waveN = wv >> 1;

  // gid -> (bm, bn); bm-pairs (gid, gid+8) share the same region -> same XCD
  const int gid = blockIdx.x;                 // 1792 blocks
  const int bm = (gid >> 3) & 1;
  const int bn = (gid & 7) | ((gid >> 4) << 3);  // [0,896)
  const int b  = bn / 28, hpair = bn - b * 28;
  const int h0 = hpair * 2;                   // output rows h0, h0+1

  // ---- A: fragment-ordered base; frag (kt,i) = aBase[kt*1024 + i*64]
  const short8* aBase = (const short8*)wtf + ((bm * 8 + waveM * 4) * 64 + lane);

  // ---- B: per-lane region byte offsets, per (j, kw); kh/ci32 are immediates
  int baddr[4][3];
#pragma unroll
  for (int j = 0; j < 4; ++j) {
    const int np = waveN * 64 + j * 16 + fm;   // n' in [0,128)
    const int hh = np >> 6, wj = np & 63;
#pragma unroll
    for (int kw = 0; kw < 3; ++kw) {
      const int wcl = (wj + kw > 63) ? 63 : wj + kw;   // clamp garbage cols
      baddr[j][kw] = (hh * 64 + wcl) * PIXSTRIDE + q * 16;
    }
  }

  floatx4 acc[4][4];
#pragma unroll
  for (int i = 0; i < 4; ++i)
#pragma unroll
    for (int j = 0; j < 4; ++j) acc[i][j] = (floatx4){0.f, 0.f, 0.f, 0.f};

  // prologue: prefetch A chunk 0
  short8 afr[2][4];
#pragma unroll
  for (int i = 0; i < 4; ++i) afr[0][i] = aBase[0 * 1024 + i * 64];

  // staging source: thread t owns region pixel slot t = (r, w'); w'>=58 -> zeros
  const int sr = tid >> 6, sw = tid & 63;
  const bool swv = (sw < WP);
  const __hip_bfloat16* srow = xp + ((size_t)(b * HP + h0 + sr) * WP + (swv ? sw : 0)) * CIN;
  char* dst = region + tid * PIXSTRIDE;

  for (int hf = 0; hf < 2; ++hf) {            // ci-half
    if (hf) __syncthreads();                  // all reads of half 0 done
    if (swv) {                                // stage 64 ci (128B) for this pixel
      const uint4* gs = (const uint4*)(srow + hf * 64);
#pragma unroll
      for (int c = 0; c < 8; ++c) *(uint4*)(dst + c * 16) = gs[c];
    } else {                                  // garbage slot: zeros
      const uint4 z = {0u, 0u, 0u, 0u};
#pragma unroll
      for (int c = 0; c < 8; ++c) *(uint4*)(dst + c * 16) = z;
    }
    __syncthreads();

#pragma unroll
    for (int c18 = 0; c18 < 18; ++c18) {
      const int kt = hf * 18 + c18;
      const int kh = c18 / 6, rem2 = c18 % 6, kw = rem2 >> 1, ci32 = (rem2 & 1) * 32;

      // prefetch A for next chunk (registers only, no barrier interaction)
      if (kt + 1 < NCHUNK) {
#pragma unroll
        for (int i = 0; i < 4; ++i) afr[(kt + 1) & 1][i] = aBase[(kt + 1) * 1024 + i * 64];
      }

      short8 bfr[4];
#pragma unroll
      for (int j = 0; j < 4; ++j)
        bfr[j] = *(const short8*)(region + baddr[j][kw] + kh * (64 * PIXSTRIDE) + ci32 * 2);

#pragma unroll
      for (int i = 0; i < 4; ++i)
#pragma unroll
        for (int j = 0; j < 4; ++j)
          acc[i][j] = __builtin_amdgcn_mfma_f32_16x16x32_bf16(afr[kt & 1][i], bfr[j],
                                                              acc[i][j], 0, 0, 0);
    }
  }

  // ---- epilogue: D col = lane&15 (n'), row = (lane>>4)*4 + reg (m); mask w>=56
  const int col = lane & 15, quad = lane >> 4;
  const int m0 = bm * 128;
#pragma unroll
  for (int j = 0; j < 4; ++j) {
    const int np = waveN * 64 + j * 16 + col;
    const int hh = np >> 6, w = np & 63;
    if (w < 56) {
      const size_t base = ((size_t)b * COUT * 3136) + (size_t)(h0 + hh) * 56 + w;
#pragma unroll
      for (int i = 0; i < 4; ++i) {
        const int co0 = m0 + waveM * 64 + i * 16 + quad * 4;
        const floatx4 b4 = *(const floatx4*)&bias[co0];
#pragma unroll
        for (int r = 0; r < 4; ++r) {
          y[base + (size_t)(co0 + r) * 3136] = acc[i][j][r] + b4[r];
        }
      }
    }
  }
}

extern "C" void kernel_launch(void* const* d_in, const int* in_sizes, int n_in,
                              void* d_out, int out_size, void* d_ws, size_t ws_size,
                              hipStream_t stream) {
  const float* x = (const float*)d_in[0];
  const float* w = (const float*)d_in[1];
  const float* b = (const float*)d_in[2];
  float* y = (float*)d_out;

  // ws footprint: 27,541,504 + 589,824 = 28,131,328 B — identical to R1-R3 (proven safe)
  const size_t xpad_bytes = (size_t)Bn * HP * ROWB * sizeof(__hip_bfloat16);
  __hip_bfloat16* xp  = (__hip_bfloat16*)d_ws;
  __hip_bfloat16* wtf = (__hip_bfloat16*)((char*)d_ws + xpad_bytes);

  xform_x<<<Bn * HP, 256, 0, stream>>>(x, xp);
  xform_w<<<(COUT * 1152) / 256, 256, 0, stream>>>(w, wtf);
  conv_gemm<<<Bn * 28 * 2, 256, 0, stream>>>(wtf, xp, b, y);
}

// Round 7
// 207.794 us; speedup vs baseline: 1.7809x; 1.3695x over previous
//
#include <hip/hip_runtime.h>
#include <hip/hip_bf16.h>
#include <stdint.h>

// Problem constants
#define Bn   32
#define CIN  128
#define Hh   56
#define Ww   56
#define COUT 256
#define HP   58            // padded rows (1 top + 1 bottom)
#define WP   58            // padded width: 0=pad, 1..56 data, 57=pad (PROVEN 28.1MB ws footprint)
#define ROWB (WP*CIN)      // 7424 elements per padded row
#define NCHUNK 36          // K chunks of 32, order kt = hf*18 + kh*6 + kw*2 + c

typedef __attribute__((ext_vector_type(8))) short short8;     // 8 x bf16
typedef __attribute__((ext_vector_type(4))) float floatx4;

__device__ __forceinline__ void async_copy16(const void* g, void* l) {
  // global -> LDS direct copy: GLOBAL address is PER-LANE (supply lane-dependent
  // pointer!); LDS dest = wave-uniform base + lane*16.  [m104/m108]
  __builtin_amdgcn_global_load_lds(
      (const __attribute__((address_space(1))) uint32_t*)g,
      (__attribute__((address_space(3))) uint32_t*)l, 16, 0, 0);
}

// ---------------------------------------------------------------------------
// Pre-pass 1 (R2-proven): x NCHW fp32 -> zero-padded NHWC bf16 xpad[b][hp][w'][ci]
// ---------------------------------------------------------------------------
__global__ __launch_bounds__(256) void xform_x(const float* __restrict__ x,
                                               __hip_bfloat16* __restrict__ xp) {
  __shared__ __hip_bfloat16 t[WP * 130];   // [w_out][ci]
  const int bid = blockIdx.x;              // 32*58 blocks
  const int b = bid / HP, hp = bid % HP;
  const size_t obase = (size_t)bid * ROWB;
  const int tid = threadIdx.x;

  if (hp == 0 || hp == HP - 1) {           // top/bottom pad rows
    uint4 z = {0u, 0u, 0u, 0u};
    uint4* o = (uint4*)(xp + obase);
    for (int i = tid; i < ROWB / 8; i += 256) o[i] = z;
    return;
  }
  const int h = hp - 1;

  { // zero w_out rows 0 and 57 (left/right pad)
    const int r = (tid >> 7) * (WP - 1);
    const int ci = tid & 127;
    t[r * 130 + ci] = __float2bfloat16(0.0f);
  }
  const float* xrow = x + (size_t)b * (CIN * Hh * Ww) + h * Ww;
  for (int i = tid; i < CIN * 14; i += 256) {
    const int ci = i / 14, wq = i - ci * 14;
    const float4 v = *(const float4*)(xrow + (size_t)ci * (Hh * Ww) + wq * 4);
    const int wr = 1 + wq * 4;
    t[(wr + 0) * 130 + ci] = __float2bfloat16(v.x);
    t[(wr + 1) * 130 + ci] = __float2bfloat16(v.y);
    t[(wr + 2) * 130 + ci] = __float2bfloat16(v.z);
    t[(wr + 3) * 130 + ci] = __float2bfloat16(v.w);
  }
  __syncthreads();
  for (int i = tid; i < ROWB / 8; i += 256) {
    const int wo = i >> 4, c8 = (i & 15) * 8;
    const uint32_t* src = (const uint32_t*)&t[wo * 130 + c8];
    uint4 d;
    d.x = src[0]; d.y = src[1]; d.z = src[2]; d.w = src[3];
    *(uint4*)(xp + obase + (size_t)wo * CIN + c8) = d;
  }
}

// ---------------------------------------------------------------------------
// Pre-pass 2 (R5-proven): weights OIHW fp32 -> FRAGMENT-ORDERED wtf.
//   wtf[kt][mb][lane][e]: A-frag chunk kt, m-block mb (16 rows) = contiguous
//   1KB; one wave-level async copy stages it already in fragment layout.
//   kt = hf*18 + kh*6 + kw*2 + c ; k-in-chunk = q*8 + e -> ci = hf*64+c*32+q*8+e
// ---------------------------------------------------------------------------
__global__ __launch_bounds__(256) void xform_w(const float* __restrict__ w,
                                               __hip_bfloat16* __restrict__ wtf) {
  const int o = blockIdx.x * 256 + threadIdx.x;   // grid = 294912/256 = 1152
  const int e = o & 7, lane = (o >> 3) & 63, mb = (o >> 9) & 15, kt = o >> 13;
  const int q = lane >> 4, fm = lane & 15;
  const int hf = kt / 18, rem = kt % 18;
  const int kh = rem / 6, rem2 = rem % 6, kw = rem2 >> 1, c = rem2 & 1;
  const int m = mb * 16 + fm;
  const int ci = hf * 64 + c * 32 + q * 8 + e;
  wtf[o] = __float2bfloat16(w[((m * CIN + ci) * 3 + kh) * 3 + kw]);
}

// ---------------------------------------------------------------------------
// Conv GEMM: R2 structure + single-barrier double-buffered LDS + frag-ordered A.
//   128x128 tile, 4 waves x (4x4 of 16x16x32 bf16). BK=32, 36 iters,
//   ONE barrier per iter; stage(kt+1) issued before MFMA(kt) -> drain ~free.
//   LDS 2 x (8KB A + 8KB B) = 32KB. __launch_bounds__(256,3) -> 3 blocks/CU.
// ---------------------------------------------------------------------------
__global__ __launch_bounds__(256, 3) void conv_gemm(const __hip_bfloat16* __restrict__ wtf,
                                                    const __hip_bfloat16* __restrict__ xp,
                                                    const float* __restrict__ bias,
                                                    float* __restrict__ y) {
  __shared__ __align__(16) char Ab[2][8192];   // [buf][mb' 0..7][lane][16B]
  __shared__ __align__(16) char Bb[2][8192];   // [buf][pixel 0..127][64B]

  const int tid  = threadIdx.x;
  const int lane = tid & 63, wv = tid >> 6;
  const int fm = lane & 15, q = lane >> 4;
  const int waveM = wv & 1, waveN = wv >> 1;

  // XCD swizzle: gid, gid+8 share bn (same B tile) on one XCD. Bijective/1568.
  const int gid = blockIdx.x;
  const int bm = (gid >> 3) & 1;
  const int bn = (gid & 7) | ((gid >> 4) << 3);   // [0,784)
  const int m0 = bm * 128, n0 = bn * 128;

  // ---- A staging source: PER-LANE address (R6 bug: was wave-uniform).
  //   lane l covers bytes [lane*16, lane*16+16) of this wave's 2KB chunk slice.
  const char* aSrc = (const char*)wtf + (size_t)bm * 8192 + wv * 2048 + lane * 16;

  // ---- B staging sources: 2 pixel-groups of 16 per wave (per-lane already)
  const __hip_bfloat16* bSrc[2];
#pragma unroll
  for (int c = 0; c < 2; ++c) {
    const int sr = wv * 32 + c * 16 + (lane >> 2);     // pixel row in tile
    const int n_r = n0 + sr;
    const int b = n_r / 3136, r = n_r - b * 3136, h = r / 56, w = r - h * 56;
    bSrc[c] = xp + (size_t)((b * HP + h) * WP + w) * CIN + (lane & 3) * 8;
  }

  floatx4 acc[4][4];
#pragma unroll
  for (int i = 0; i < 4; ++i)
#pragma unroll
    for (int j = 0; j < 4; ++j) acc[i][j] = (floatx4){0.f, 0.f, 0.f, 0.f};

#define STAGE(KT, BUF)                                                          \
  do {                                                                          \
    const int _kt = (KT);                                                       \
    const int _rem = _kt % 18, _kh = _rem / 6, _r2 = _rem % 6;                  \
    const int _kw = _r2 >> 1, _ci0 = (_kt / 18) * 64 + (_r2 & 1) * 32;          \
    const int _bOff = (_kh * WP + _kw) * CIN + _ci0;                            \
    async_copy16(aSrc + (size_t)_kt * 16384, Ab[BUF] + wv * 2048);              \
    async_copy16(aSrc + (size_t)_kt * 16384 + 1024, Ab[BUF] + wv * 2048 + 1024);\
    async_copy16(bSrc[0] + _bOff, Bb[BUF] + wv * 2048);                         \
    async_copy16(bSrc[1] + _bOff, Bb[BUF] + wv * 2048 + 1024);                  \
  } while (0)

  STAGE(0, 0);   // prologue

#pragma unroll 2
  for (int kt = 0; kt < NCHUNK; ++kt) {
    const int buf = kt & 1;
    __syncthreads();                 // buffer `buf` ready; prior reads done
    if (kt + 1 < NCHUNK) STAGE(kt + 1, buf ^ 1);   // fire-and-forget for next iter

    short8 a[4], b[4];
#pragma unroll
    for (int i = 0; i < 4; ++i)
      a[i] = *(const short8*)(Ab[buf] + (waveM * 4 + i) * 1024 + lane * 16);
#pragma unroll
    for (int j = 0; j < 4; ++j)
      b[j] = *(const short8*)(Bb[buf] + (waveN * 64 + j * 16 + fm) * 64 + q * 16);
#pragma unroll
    for (int i = 0; i < 4; ++i)
#pragma unroll
      for (int j = 0; j < 4; ++j)
        acc[i][j] = __builtin_amdgcn_mfma_f32_16x16x32_bf16(a[i], b[j], acc[i][j], 0, 0, 0);
  }
#undef STAGE

  // ---- epilogue: D col = lane&15 (n), row = (lane>>4)*4 + reg (m)
  const int col = lane & 15, quad = lane >> 4;
#pragma unroll
  for (int j = 0; j < 4; ++j) {
    const int n = n0 + waveN * 64 + j * 16 + col;
    const int bb = n / 3136, nr = n - bb * 3136;
    const size_t base = (size_t)bb * (COUT * 3136) + nr;
#pragma unroll
    for (int i = 0; i < 4; ++i) {
      const int co0 = m0 + waveM * 64 + i * 16 + quad * 4;
      const floatx4 b4 = *(const floatx4*)&bias[co0];
#pragma unroll
      for (int r = 0; r < 4; ++r) {
        y[base + (size_t)(co0 + r) * 3136] = acc[i][j][r] + b4[r];
      }
    }
  }
}

extern "C" void kernel_launch(void* const* d_in, const int* in_sizes, int n_in,
                              void* d_out, int out_size, void* d_ws, size_t ws_size,
                              hipStream_t stream) {
  const float* x = (const float*)d_in[0];
  const float* w = (const float*)d_in[1];
  const float* b = (const float*)d_in[2];
  float* y = (float*)d_out;

  // ws footprint: 27,541,504 + 589,824 = 28,131,328 B — identical to R1-R3 (proven safe)
  const size_t xpad_bytes = (size_t)Bn * HP * ROWB * sizeof(__hip_bfloat16);
  __hip_bfloat16* xp  = (__hip_bfloat16*)d_ws;
  __hip_bfloat16* wtf = (__hip_bfloat16*)((char*)d_ws + xpad_bytes);

  xform_x<<<Bn * HP, 256, 0, stream>>>(x, xp);
  xform_w<<<(COUT * 1152) / 256, 256, 0, stream>>>(w, wtf);
  conv_gemm<<<2 * ((Bn * Hh * Ww) / 128), 256, 0, stream>>>(wtf, xp, b, y);
}